// Round 1
// baseline (921.429 us; speedup 1.0000x reference)
//
#include <hip/hip_runtime.h>
#include <cstdint>
#include <cstddef>

typedef unsigned short u16;
typedef __attribute__((ext_vector_type(8))) short short8;
typedef __attribute__((ext_vector_type(4))) float floatx4;

__device__ __forceinline__ u16 f2bf(float f) {
  unsigned u = __float_as_uint(f);
  u += 0x7fffu + ((u >> 16) & 1u);
  return (u16)(u >> 16);
}
__device__ __forceinline__ float bf2f(u16 s) {
  return __uint_as_float(((unsigned)s) << 16);
}

// ---------------- LayerNorm (f32 in) -> bf16 x ----------------
__global__ __launch_bounds__(256) void ln_kernel(const float* __restrict__ x,
                                                 const float* __restrict__ g,
                                                 const float* __restrict__ bta,
                                                 u16* __restrict__ out) {
  const int row = blockIdx.x;
  const int tid = threadIdx.x;
  const float4 v = ((const float4*)(x + (size_t)row * 1024))[tid];
  float s = v.x + v.y + v.z + v.w;
#pragma unroll
  for (int o = 32; o > 0; o >>= 1) s += __shfl_down(s, o);
  __shared__ float red[4], red2[4];
  const int wv = tid >> 6, ln = tid & 63;
  if (ln == 0) red[wv] = s;
  __syncthreads();
  const float mean = (red[0] + red[1] + red[2] + red[3]) * (1.0f / 1024.0f);
  const float dx = v.x - mean, dy = v.y - mean, dz = v.z - mean, dw = v.w - mean;
  float s2 = dx * dx + dy * dy + dz * dz + dw * dw;
#pragma unroll
  for (int o = 32; o > 0; o >>= 1) s2 += __shfl_down(s2, o);
  if (ln == 0) red2[wv] = s2;
  __syncthreads();
  const float var = (red2[0] + red2[1] + red2[2] + red2[3]) * (1.0f / 1024.0f);
  const float rstd = rsqrtf(var + 1e-6f);
  const float4 gg = ((const float4*)g)[tid];
  const float4 bb = ((const float4*)bta)[tid];
  ushort4 o4;
  o4.x = f2bf(dx * rstd * gg.x + bb.x);
  o4.y = f2bf(dy * rstd * gg.y + bb.y);
  o4.z = f2bf(dz * rstd * gg.z + bb.z);
  o4.w = f2bf(dw * rstd * gg.w + bb.w);
  ((ushort4*)(out + (size_t)row * 1024))[tid] = o4;
}

// ---------------- W (KxN f32) -> WT (NxK bf16) ----------------
__global__ __launch_bounds__(256) void transpose_bf16(const float* __restrict__ W,
                                                      u16* __restrict__ WT,
                                                      int K, int N) {
  __shared__ float t[32][33];
  const int kb = blockIdx.x * 32, nb = blockIdx.y * 32;
  const int tx = threadIdx.x & 31, ty = threadIdx.x >> 5;
#pragma unroll
  for (int i = ty; i < 32; i += 8) t[i][tx] = W[(size_t)(kb + i) * N + nb + tx];
  __syncthreads();
#pragma unroll
  for (int i = ty; i < 32; i += 8) WT[(size_t)(nb + i) * K + kb + tx] = f2bf(t[tx][i]);
}

// ---------------- big bf16 MFMA GEMM: C = A(MxK) * BT(NxK)^T + bias ----------------
// EPI 0: store bf16 to outB.  EPI 1: store f32 (acc + bias + extra) to outF.
template <int EPI>
__global__ __launch_bounds__(256) void gemm_bf16(const u16* __restrict__ A,
                                                 const u16* __restrict__ BT,
                                                 const float* __restrict__ bias,
                                                 const float* __restrict__ extra,
                                                 u16* __restrict__ outB,
                                                 float* __restrict__ outF,
                                                 int M, int N, int K) {
  __shared__ u16 sA[128 * 64];
  __shared__ u16 sB[128 * 64];
  const int tid = threadIdx.x;
  const int wave = tid >> 6, lane = tid & 63;
  const int m0 = blockIdx.x * 128, n0 = blockIdx.y * 128;
  const int wm = (wave >> 1) * 64, wn = (wave & 1) * 64;

  floatx4 acc[4][4];
  const floatx4 zero = {0.f, 0.f, 0.f, 0.f};
#pragma unroll
  for (int i = 0; i < 4; ++i)
#pragma unroll
    for (int j = 0; j < 4; ++j) acc[i][j] = zero;

  const int srow = wave * 32 + (lane >> 3);  // + i*8
  const int sslot = lane & 7;

  for (int kt = 0; kt < K; kt += 64) {
    // stage A tile (128x64 bf16), XOR-swizzled k-granules to dodge bank conflicts
#pragma unroll
    for (int i = 0; i < 4; ++i) {
      const int rl = srow + i * 8;
      const int gA = sslot ^ (rl & 7);
      const u16* ga = A + (size_t)(m0 + rl) * K + kt + gA * 8;
      u16* la = sA + (wave * 32 + i * 8) * 64;  // wave-uniform base
      __builtin_amdgcn_global_load_lds((const __attribute__((address_space(1))) void*)ga,
                                       (__attribute__((address_space(3))) void*)la, 16, 0, 0);
    }
#pragma unroll
    for (int i = 0; i < 4; ++i) {
      const int rl = srow + i * 8;
      const int gB = sslot ^ (rl & 7);
      const u16* gb = BT + (size_t)(n0 + rl) * K + kt + gB * 8;
      u16* lb = sB + (wave * 32 + i * 8) * 64;
      __builtin_amdgcn_global_load_lds((const __attribute__((address_space(1))) void*)gb,
                                       (__attribute__((address_space(3))) void*)lb, 16, 0, 0);
    }
    __syncthreads();
    const int fr = lane & 15, fq = lane >> 4;
#pragma unroll
    for (int ks = 0; ks < 2; ++ks) {
      short8 af[4], bfr[4];
#pragma unroll
      for (int i = 0; i < 4; ++i) {
        const int rl = wm + i * 16 + fr;
        const int g = ks * 4 + fq;
        af[i] = *(const short8*)(sA + rl * 64 + (g ^ (rl & 7)) * 8);
      }
#pragma unroll
      for (int j = 0; j < 4; ++j) {
        const int rl = wn + j * 16 + fr;
        const int g = ks * 4 + fq;
        bfr[j] = *(const short8*)(sB + rl * 64 + (g ^ (rl & 7)) * 8);
      }
#pragma unroll
      for (int i = 0; i < 4; ++i)
#pragma unroll
        for (int j = 0; j < 4; ++j)
          acc[i][j] = __builtin_amdgcn_mfma_f32_16x16x32_bf16(af[i], bfr[j], acc[i][j], 0, 0, 0);
    }
    __syncthreads();
  }

  const int fr = lane & 15, fq = lane >> 4;
#pragma unroll
  for (int i = 0; i < 4; ++i)
#pragma unroll
    for (int j = 0; j < 4; ++j)
#pragma unroll
      for (int r = 0; r < 4; ++r) {
        const int m = m0 + wm + i * 16 + fq * 4 + r;
        const int n = n0 + wn + j * 16 + fr;
        const float v = acc[i][j][r] + bias[n];
        if (EPI == 0)
          outB[(size_t)m * N + n] = f2bf(v);
        else
          outF[(size_t)m * N + n] = v + extra[(size_t)m * N + n];
      }
}

// ---------------- attention 1: anchor queries vs 2048 keys ----------------
__global__ __launch_bounds__(256) void attn1_kernel(const u16* __restrict__ qkv,
                                                    const float* __restrict__ q_anchor,
                                                    float* __restrict__ att1) {
  __shared__ float qa[8][128];   // q_anchor for this head; reused as out accumulator
  __shared__ float S[8][2048];   // scores -> probs
  const int tid = threadIdx.x;
  const int b = blockIdx.x >> 3, h = blockIdx.x & 7;
  for (int i = tid; i < 1024; i += 256) qa[i >> 7][i & 127] = q_anchor[h * 1024 + i];
  __syncthreads();
  const float scale = 0.0883883476483184f;
  // phase 1: scores
  for (int it = 0; it < 8; ++it) {
    const int n = it * 256 + tid;
    const u16* kp = qkv + (size_t)(b * 2048 + n) * 3072 + 1024 + h * 128;
    float dots[8] = {0, 0, 0, 0, 0, 0, 0, 0};
#pragma unroll 8
    for (int dd = 0; dd < 128; dd += 4) {
      const ushort4 k4 = *(const ushort4*)(kp + dd);
      const float k0 = bf2f(k4.x), k1 = bf2f(k4.y), k2 = bf2f(k4.z), k3 = bf2f(k4.w);
#pragma unroll
      for (int a = 0; a < 8; ++a) {
        const float4 q4 = *(const float4*)&qa[a][dd];
        dots[a] += q4.x * k0 + q4.y * k1 + q4.z * k2 + q4.w * k3;
      }
    }
#pragma unroll
    for (int a = 0; a < 8; ++a) S[a][n] = dots[a] * scale;
  }
  __syncthreads();
  // phase 2: row softmax (32 lanes per row)
  {
    const int a = tid >> 5, l = tid & 31;
    float mx = -1e30f;
    for (int n = l; n < 2048; n += 32) mx = fmaxf(mx, S[a][n]);
#pragma unroll
    for (int o = 16; o > 0; o >>= 1) mx = fmaxf(mx, __shfl_xor(mx, o, 32));
    float sum = 0.f;
    for (int n = l; n < 2048; n += 32) {
      const float e = __expf(S[a][n] - mx);
      S[a][n] = e;
      sum += e;
    }
#pragma unroll
    for (int o = 16; o > 0; o >>= 1) sum += __shfl_xor(sum, o, 32);
    const float inv = 1.f / sum;
    for (int n = l; n < 2048; n += 32) S[a][n] *= inv;
  }
  __syncthreads();
  // phase 3: out[a][d] = sum_n S[a][n] * V[n][d]
  {
    const int d = tid & 127, half = tid >> 7;
    const u16* vp = qkv + (size_t)b * 2048 * 3072 + 2048 + h * 128 + d;
    float acc[8] = {0.f};
    const int nbeg = half * 1024;
    for (int n = nbeg; n < nbeg + 1024; n += 4) {
      const float v0 = bf2f(vp[(size_t)n * 3072]);
      const float v1 = bf2f(vp[(size_t)(n + 1) * 3072]);
      const float v2 = bf2f(vp[(size_t)(n + 2) * 3072]);
      const float v3 = bf2f(vp[(size_t)(n + 3) * 3072]);
#pragma unroll
      for (int a = 0; a < 8; ++a) {
        const float4 s4 = *(const float4*)&S[a][n];
        acc[a] += s4.x * v0 + s4.y * v1 + s4.z * v2 + s4.w * v3;
      }
    }
    if (half == 0) {
#pragma unroll
      for (int a = 0; a < 8; ++a) qa[a][d] = acc[a];
    }
    __syncthreads();
    if (half == 1) {
#pragma unroll
      for (int a = 0; a < 8; ++a) qa[a][d] += acc[a];
    }
    __syncthreads();
    for (int i = tid; i < 1024; i += 256)
      att1[(size_t)blockIdx.x * 1024 + i] = qa[i >> 7][i & 127];
  }
}

// ---------------- bias init for atomic split-K GEMMs ----------------
__global__ __launch_bounds__(256) void init_bias(float* __restrict__ C,
                                                 const float* __restrict__ bias,
                                                 int N, int permuted, int total) {
  const int idx = blockIdx.x * 256 + threadIdx.x;
  if (idx >= total) return;
  const int row = idx / N, col = idx - row * N;
  float v;
  if (!permuted)
    v = bias[col];
  else
    v = bias[(row & 7) * 512 + (col & 511)];  // b_an at f = a*512 + jj
  C[idx] = v;
}

// ---------------- small-M (64) f32 GEMM, split-K with atomic accumulate ----------------
// C(64xN) += A(64xK chunk) @ W(KxN chunk); relu applied to A on load if reluA.
// permOut: write to permuted (b,NA,H*512) layout (an-layer).
__global__ __launch_bounds__(256) void mlp_gemm(const float* __restrict__ A,
                                                const float* __restrict__ W,
                                                float* __restrict__ C,
                                                int K, int N, int reluA, int permOut) {
  __shared__ float sAT[64][68];  // [k][m]
  __shared__ float sW[64][68];   // [k][n]
  const int tid = threadIdx.x;
  const int n0 = blockIdx.x * 64;
  const int tx = tid & 15, ty = tid >> 4;
  float acc[4][4] = {};
  const int kbeg = blockIdx.y * 512, kend = kbeg + 512;
  for (int k0 = kbeg; k0 < kend; k0 += 64) {
    for (int i = tid; i < 4096; i += 256) {
      const int m = i >> 6, kk = i & 63;
      const float a = A[(size_t)m * K + k0 + kk];
      sAT[kk][m] = reluA ? fmaxf(a, 0.f) : a;
      sW[m][kk] = W[(size_t)(k0 + m) * N + n0 + kk];  // reuse decomposition: row m is k-row
    }
    __syncthreads();
#pragma unroll 4
    for (int k = 0; k < 64; ++k) {
      const float4 av = *(const float4*)&sAT[k][ty * 4];
      const float4 wv = *(const float4*)&sW[k][tx * 4];
      const float aa[4] = {av.x, av.y, av.z, av.w};
      const float ww[4] = {wv.x, wv.y, wv.z, wv.w};
#pragma unroll
      for (int i = 0; i < 4; ++i)
#pragma unroll
        for (int j = 0; j < 4; ++j) acc[i][j] += aa[i] * ww[j];
    }
    __syncthreads();
  }
#pragma unroll
  for (int i = 0; i < 4; ++i)
#pragma unroll
    for (int j = 0; j < 4; ++j) {
      const int row = ty * 4 + i;
      const int col = n0 + tx * 4 + j;
      size_t idx;
      if (!permOut) {
        idx = (size_t)row * N + col;
      } else {
        const int bb = row >> 3, hh = row & 7, a2 = col >> 9, jj = col & 511;
        idx = (size_t)(bb * 8 + a2) * 4096 + hh * 512 + jj;
      }
      atomicAdd(&C[idx], acc[i][j]);
    }
}

// ---------------- attention 2: 2048 queries vs 8 anchor keys + PV ----------------
__global__ __launch_bounds__(256) void attn2_kernel(const u16* __restrict__ qkv,
                                                    const float* __restrict__ kk,
                                                    const float* __restrict__ onet,
                                                    u16* __restrict__ y) {
  __shared__ float kkl[8][128];
  __shared__ float ovl[8][128];
  const int tid = threadIdx.x;
  const int chunk = blockIdx.x & 7, bh = blockIdx.x >> 3;
  const int b = bh >> 3, h = bh & 7;
  for (int i = tid; i < 1024; i += 256) {
    const int a = i >> 7, d = i & 127;
    kkl[a][d] = kk[(size_t)(b * 8 + a) * 1024 + h * 128 + d];
    ovl[a][d] = onet[(size_t)(b * 8 + a) * 1024 + h * 128 + d];
  }
  __syncthreads();
  const int n = chunk * 256 + tid;
  const u16* qp = qkv + (size_t)(b * 2048 + n) * 3072 + h * 128;
  float dots[8] = {0, 0, 0, 0, 0, 0, 0, 0};
#pragma unroll 4
  for (int dd = 0; dd < 128; dd += 4) {
    const ushort4 q4 = *(const ushort4*)(qp + dd);
    const float q0 = bf2f(q4.x), q1 = bf2f(q4.y), q2 = bf2f(q4.z), q3 = bf2f(q4.w);
#pragma unroll
    for (int a = 0; a < 8; ++a) {
      const float4 k4 = *(const float4*)&kkl[a][dd];
      dots[a] += k4.x * q0 + k4.y * q1 + k4.z * q2 + k4.w * q3;
    }
  }
  const float scale = 0.0883883476483184f;
  float mx = -1e30f;
#pragma unroll
  for (int a = 0; a < 8; ++a) {
    dots[a] *= scale;
    mx = fmaxf(mx, dots[a]);
  }
  float p[8];
  float sum = 0.f;
#pragma unroll
  for (int a = 0; a < 8; ++a) {
    p[a] = __expf(dots[a] - mx);
    sum += p[a];
  }
  const float inv = 1.f / sum;
#pragma unroll
  for (int a = 0; a < 8; ++a) p[a] *= inv;
  u16* yp = y + (size_t)(b * 2048 + n) * 1024 + h * 128;
#pragma unroll 4
  for (int dd = 0; dd < 128; dd += 4) {
    float a0 = 0, a1 = 0, a2 = 0, a3 = 0;
#pragma unroll
    for (int a = 0; a < 8; ++a) {
      const float4 o4 = *(const float4*)&ovl[a][dd];
      a0 += p[a] * o4.x;
      a1 += p[a] * o4.y;
      a2 += p[a] * o4.z;
      a3 += p[a] * o4.w;
    }
    ushort4 o;
    o.x = f2bf(a0);
    o.y = f2bf(a1);
    o.z = f2bf(a2);
    o.w = f2bf(a3);
    *(ushort4*)(yp + dd) = o;
  }
}

extern "C" void kernel_launch(void* const* d_in, const int* in_sizes, int n_in,
                              void* d_out, int out_size, void* d_ws, size_t ws_size,
                              hipStream_t stream) {
  const float* inputs = (const float*)d_in[0];
  const float* ln_g = (const float*)d_in[1];
  const float* ln_b = (const float*)d_in[2];
  const float* q_anchor = (const float*)d_in[3];
  const float* W_qkv = (const float*)d_in[4];
  const float* b_qkv = (const float*)d_in[5];
  const float* W_an = (const float*)d_in[6];
  const float* b_an = (const float*)d_in[7];
  const float* W_n1 = (const float*)d_in[8];
  const float* b_n1 = (const float*)d_in[9];
  const float* W_n2 = (const float*)d_in[10];
  const float* b_n2 = (const float*)d_in[11];
  const float* W_n3 = (const float*)d_in[12];
  const float* b_n3 = (const float*)d_in[13];
  const float* W_k = (const float*)d_in[14];
  const float* b_k = (const float*)d_in[15];
  const float* W_o = (const float*)d_in[16];
  const float* b_o = (const float*)d_in[17];
  float* out = (float*)d_out;

  char* ws = (char*)d_ws;
  u16* qkv = (u16*)(ws);                                   // 16384*3072 bf16 = 96 MB
  u16* xbf = (u16*)(ws + 100663296);                       // 16384*1024 bf16 (x, later y)
  u16* WqkvT = (u16*)(ws + 100663296 + 33554432);          // 3072*1024 bf16
  u16* WoT = (u16*)(ws + 140509184);                       // 1024*1024 bf16
  float* att1 = (float*)(ws + 142606336);                  // 64*1024
  float* anp = (float*)(ws + 142868480);                   // 64*4096 (permuted an out)
  float* h1 = (float*)(ws + 143917056);                    // 64*1024
  float* h2 = (float*)(ws + 144179200);                    // 64*4096
  float* onet = (float*)(ws + 145227776);                  // 64*1024
  float* kkb = (float*)(ws + 145489920);                   // 64*1024

  // 1) LayerNorm -> x bf16
  ln_kernel<<<16384, 256, 0, stream>>>(inputs, ln_g, ln_b, xbf);
  // 2) weight transpose/convert
  transpose_bf16<<<dim3(32, 96), 256, 0, stream>>>(W_qkv, WqkvT, 1024, 3072);
  transpose_bf16<<<dim3(32, 32), 256, 0, stream>>>(W_o, WoT, 1024, 1024);
  // 3) QKV GEMM -> qkv bf16
  gemm_bf16<0><<<dim3(128, 24), 256, 0, stream>>>(xbf, WqkvT, b_qkv, nullptr, qkv, nullptr,
                                                  16384, 3072, 1024);
  // 4) anchor attention
  attn1_kernel<<<64, 256, 0, stream>>>(qkv, q_anchor, att1);
  // 5) MLP chain (split-K atomic GEMMs, bias pre-init, relu folded into consumer A-load)
  init_bias<<<1024, 256, 0, stream>>>(anp, b_an, 4096, 1, 64 * 4096);
  init_bias<<<256, 256, 0, stream>>>(h1, b_n1, 1024, 0, 64 * 1024);
  init_bias<<<1024, 256, 0, stream>>>(h2, b_n2, 4096, 0, 64 * 4096);
  init_bias<<<256, 256, 0, stream>>>(onet, b_n3, 1024, 0, 64 * 1024);
  init_bias<<<256, 256, 0, stream>>>(kkb, b_k, 1024, 0, 64 * 1024);
  mlp_gemm<<<dim3(64, 2), 256, 0, stream>>>(att1, W_an, anp, 1024, 4096, 0, 1);
  mlp_gemm<<<dim3(16, 8), 256, 0, stream>>>(anp, W_n1, h1, 4096, 1024, 1, 0);   // relu(an)
  mlp_gemm<<<dim3(64, 2), 256, 0, stream>>>(h1, W_n2, h2, 1024, 4096, 0, 0);
  mlp_gemm<<<dim3(16, 8), 256, 0, stream>>>(h2, W_n3, onet, 4096, 1024, 1, 0);  // relu(h2)
  mlp_gemm<<<dim3(16, 2), 256, 0, stream>>>(onet, W_k, kkb, 1024, 1024, 0, 0);
  // 6) query attention over 8 anchors -> y bf16 (reuses xbf buffer)
  attn2_kernel<<<512, 256, 0, stream>>>(qkv, kkb, onet, xbf);
  // 7) output GEMM + bias + residual -> d_out f32
  gemm_bf16<1><<<dim3(128, 8), 256, 0, stream>>>(xbf, WoT, b_o, inputs, nullptr, out,
                                                 16384, 1024, 1024);
}

// Round 2
// 820.499 us; speedup vs baseline: 1.1230x; 1.1230x over previous
//
#include <hip/hip_runtime.h>
#include <cstdint>
#include <cstddef>

typedef unsigned short u16;
typedef __attribute__((ext_vector_type(8))) short short8;
typedef __attribute__((ext_vector_type(4))) float floatx4;

__device__ __forceinline__ u16 f2bf(float f) {
  unsigned u = __float_as_uint(f);
  u += 0x7fffu + ((u >> 16) & 1u);
  return (u16)(u >> 16);
}
__device__ __forceinline__ float bf2f(u16 s) {
  return __uint_as_float(((unsigned)s) << 16);
}

// ---------------- LayerNorm (f32 in) -> bf16 x ----------------
__global__ __launch_bounds__(256) void ln_kernel(const float* __restrict__ x,
                                                 const float* __restrict__ g,
                                                 const float* __restrict__ bta,
                                                 u16* __restrict__ out) {
  const int row = blockIdx.x;
  const int tid = threadIdx.x;
  const float4 v = ((const float4*)(x + (size_t)row * 1024))[tid];
  float s = v.x + v.y + v.z + v.w;
#pragma unroll
  for (int o = 32; o > 0; o >>= 1) s += __shfl_down(s, o);
  __shared__ float red[4], red2[4];
  const int wv = tid >> 6, ln = tid & 63;
  if (ln == 0) red[wv] = s;
  __syncthreads();
  const float mean = (red[0] + red[1] + red[2] + red[3]) * (1.0f / 1024.0f);
  const float dx = v.x - mean, dy = v.y - mean, dz = v.z - mean, dw = v.w - mean;
  float s2 = dx * dx + dy * dy + dz * dz + dw * dw;
#pragma unroll
  for (int o = 32; o > 0; o >>= 1) s2 += __shfl_down(s2, o);
  if (ln == 0) red2[wv] = s2;
  __syncthreads();
  const float var = (red2[0] + red2[1] + red2[2] + red2[3]) * (1.0f / 1024.0f);
  const float rstd = rsqrtf(var + 1e-6f);
  const float4 gg = ((const float4*)g)[tid];
  const float4 bb = ((const float4*)bta)[tid];
  ushort4 o4;
  o4.x = f2bf(dx * rstd * gg.x + bb.x);
  o4.y = f2bf(dy * rstd * gg.y + bb.y);
  o4.z = f2bf(dz * rstd * gg.z + bb.z);
  o4.w = f2bf(dw * rstd * gg.w + bb.w);
  ((ushort4*)(out + (size_t)row * 1024))[tid] = o4;
}

// ---------------- W (KxN f32) -> WT (NxK bf16) ----------------
__global__ __launch_bounds__(256) void transpose_bf16(const float* __restrict__ W,
                                                      u16* __restrict__ WT,
                                                      int K, int N) {
  __shared__ float t[32][33];
  const int kb = blockIdx.x * 32, nb = blockIdx.y * 32;
  const int tx = threadIdx.x & 31, ty = threadIdx.x >> 5;
#pragma unroll
  for (int i = ty; i < 32; i += 8) t[i][tx] = W[(size_t)(kb + i) * N + nb + tx];
  __syncthreads();
#pragma unroll
  for (int i = ty; i < 32; i += 8) WT[(size_t)(nb + i) * K + kb + tx] = f2bf(t[tx][i]);
}

// ---------------- big bf16 MFMA GEMM: C = A(MxK) * BT(NxK)^T + bias ----------------
template <int EPI>
__global__ __launch_bounds__(256) void gemm_bf16(const u16* __restrict__ A,
                                                 const u16* __restrict__ BT,
                                                 const float* __restrict__ bias,
                                                 const float* __restrict__ extra,
                                                 u16* __restrict__ outB,
                                                 float* __restrict__ outF,
                                                 int M, int N, int K) {
  __shared__ u16 sA[128 * 64];
  __shared__ u16 sB[128 * 64];
  const int tid = threadIdx.x;
  const int wave = tid >> 6, lane = tid & 63;
  const int m0 = blockIdx.x * 128, n0 = blockIdx.y * 128;
  const int wm = (wave >> 1) * 64, wn = (wave & 1) * 64;

  floatx4 acc[4][4];
  const floatx4 zero = {0.f, 0.f, 0.f, 0.f};
#pragma unroll
  for (int i = 0; i < 4; ++i)
#pragma unroll
    for (int j = 0; j < 4; ++j) acc[i][j] = zero;

  const int srow = wave * 32 + (lane >> 3);
  const int sslot = lane & 7;

  for (int kt = 0; kt < K; kt += 64) {
#pragma unroll
    for (int i = 0; i < 4; ++i) {
      const int rl = srow + i * 8;
      const int gA = sslot ^ (rl & 7);
      const u16* ga = A + (size_t)(m0 + rl) * K + kt + gA * 8;
      u16* la = sA + (wave * 32 + i * 8) * 64;
      __builtin_amdgcn_global_load_lds((const __attribute__((address_space(1))) void*)ga,
                                       (__attribute__((address_space(3))) void*)la, 16, 0, 0);
    }
#pragma unroll
    for (int i = 0; i < 4; ++i) {
      const int rl = srow + i * 8;
      const int gB = sslot ^ (rl & 7);
      const u16* gb = BT + (size_t)(n0 + rl) * K + kt + gB * 8;
      u16* lb = sB + (wave * 32 + i * 8) * 64;
      __builtin_amdgcn_global_load_lds((const __attribute__((address_space(1))) void*)gb,
                                       (__attribute__((address_space(3))) void*)lb, 16, 0, 0);
    }
    __syncthreads();
    const int fr = lane & 15, fq = lane >> 4;
#pragma unroll
    for (int ks = 0; ks < 2; ++ks) {
      short8 af[4], bfr[4];
#pragma unroll
      for (int i = 0; i < 4; ++i) {
        const int rl = wm + i * 16 + fr;
        const int g = ks * 4 + fq;
        af[i] = *(const short8*)(sA + rl * 64 + (g ^ (rl & 7)) * 8);
      }
#pragma unroll
      for (int j = 0; j < 4; ++j) {
        const int rl = wn + j * 16 + fr;
        const int g = ks * 4 + fq;
        bfr[j] = *(const short8*)(sB + rl * 64 + (g ^ (rl & 7)) * 8);
      }
#pragma unroll
      for (int i = 0; i < 4; ++i)
#pragma unroll
        for (int j = 0; j < 4; ++j)
          acc[i][j] = __builtin_amdgcn_mfma_f32_16x16x32_bf16(af[i], bfr[j], acc[i][j], 0, 0, 0);
    }
    __syncthreads();
  }

  const int fr = lane & 15, fq = lane >> 4;
#pragma unroll
  for (int i = 0; i < 4; ++i)
#pragma unroll
    for (int j = 0; j < 4; ++j)
#pragma unroll
      for (int r = 0; r < 4; ++r) {
        const int m = m0 + wm + i * 16 + fq * 4 + r;
        const int n = n0 + wn + j * 16 + fr;
        const float v = acc[i][j][r] + bias[n];
        if (EPI == 0)
          outB[(size_t)m * N + n] = f2bf(v);
        else
          outF[(size_t)m * N + n] = v + extra[(size_t)m * N + n];
      }
}

// ---------------- attn1 stage A: scores S[bh][a][n] ----------------
__global__ __launch_bounds__(256) void attn1_scores(const u16* __restrict__ qkv,
                                                    const float* __restrict__ q_anchor,
                                                    float* __restrict__ S) {
  __shared__ float qa[8][128];
  const int tid = threadIdx.x;
  const int chunk = blockIdx.x & 7, bh = blockIdx.x >> 3;
  const int b = bh >> 3, h = bh & 7;
  for (int i = tid; i < 1024; i += 256) qa[i >> 7][i & 127] = q_anchor[h * 1024 + i];
  __syncthreads();
  const float scale = 0.0883883476483184f;
  const int n = chunk * 256 + tid;
  const u16* kp = qkv + (size_t)(b * 2048 + n) * 3072 + 1024 + h * 128;
  float dots[8] = {0, 0, 0, 0, 0, 0, 0, 0};
#pragma unroll 8
  for (int dd = 0; dd < 128; dd += 4) {
    const ushort4 k4 = *(const ushort4*)(kp + dd);
    const float k0 = bf2f(k4.x), k1 = bf2f(k4.y), k2 = bf2f(k4.z), k3 = bf2f(k4.w);
#pragma unroll
    for (int a = 0; a < 8; ++a) {
      const float4 q4 = *(const float4*)&qa[a][dd];
      dots[a] += q4.x * k0 + q4.y * k1 + q4.z * k2 + q4.w * k3;
    }
  }
#pragma unroll
  for (int a = 0; a < 8; ++a) S[((size_t)(bh * 8 + a)) * 2048 + n] = dots[a] * scale;
}

// ---------------- attn1 stage B: row softmax over 2048, in place ----------------
__global__ __launch_bounds__(256) void attn1_softmax(float* __restrict__ S) {
  const int row = blockIdx.x;
  const int tid = threadIdx.x;
  float* Sp = S + (size_t)row * 2048;
  float4 v0 = ((const float4*)Sp)[tid * 2];
  float4 v1 = ((const float4*)Sp)[tid * 2 + 1];
  float mx = fmaxf(fmaxf(fmaxf(v0.x, v0.y), fmaxf(v0.z, v0.w)),
                   fmaxf(fmaxf(v1.x, v1.y), fmaxf(v1.z, v1.w)));
#pragma unroll
  for (int o = 32; o > 0; o >>= 1) mx = fmaxf(mx, __shfl_xor(mx, o));
  __shared__ float red[4];
  const int wv = tid >> 6, ln = tid & 63;
  if (ln == 0) red[wv] = mx;
  __syncthreads();
  mx = fmaxf(fmaxf(red[0], red[1]), fmaxf(red[2], red[3]));
  v0.x = __expf(v0.x - mx); v0.y = __expf(v0.y - mx);
  v0.z = __expf(v0.z - mx); v0.w = __expf(v0.w - mx);
  v1.x = __expf(v1.x - mx); v1.y = __expf(v1.y - mx);
  v1.z = __expf(v1.z - mx); v1.w = __expf(v1.w - mx);
  float sum = v0.x + v0.y + v0.z + v0.w + v1.x + v1.y + v1.z + v1.w;
#pragma unroll
  for (int o = 32; o > 0; o >>= 1) sum += __shfl_xor(sum, o);
  __shared__ float red2[4];
  if (ln == 0) red2[wv] = sum;
  __syncthreads();
  const float inv = 1.f / (red2[0] + red2[1] + red2[2] + red2[3]);
  v0.x *= inv; v0.y *= inv; v0.z *= inv; v0.w *= inv;
  v1.x *= inv; v1.y *= inv; v1.z *= inv; v1.w *= inv;
  ((float4*)Sp)[tid * 2] = v0;
  ((float4*)Sp)[tid * 2 + 1] = v1;
}

// ---------------- attn1 stage C: partial PV, atomic accumulate ----------------
__global__ __launch_bounds__(256) void attn1_pv(const u16* __restrict__ qkv,
                                                const float* __restrict__ S,
                                                float* __restrict__ att1) {
  __shared__ float P[8][256];
  const int tid = threadIdx.x;
  const int chunk = blockIdx.x & 7, bh = blockIdx.x >> 3;
  const int b = bh >> 3, h = bh & 7;
  for (int i = tid; i < 2048; i += 256) {
    const int a = i >> 8, n = i & 255;
    P[a][n] = S[((size_t)(bh * 8 + a)) * 2048 + chunk * 256 + n];
  }
  __syncthreads();
  const int d = tid & 127, half = tid >> 7;
  const int nbase = chunk * 256 + half * 128;
  const u16* vp = qkv + (size_t)(b * 2048 + nbase) * 3072 + 2048 + h * 128 + d;
  float acc[8] = {0.f};
  for (int n = 0; n < 128; n += 4) {
    const float v0 = bf2f(vp[(size_t)n * 3072]);
    const float v1 = bf2f(vp[(size_t)(n + 1) * 3072]);
    const float v2 = bf2f(vp[(size_t)(n + 2) * 3072]);
    const float v3 = bf2f(vp[(size_t)(n + 3) * 3072]);
#pragma unroll
    for (int a = 0; a < 8; ++a) {
      const float4 s4 = *(const float4*)&P[a][half * 128 + n];
      acc[a] += s4.x * v0 + s4.y * v1 + s4.z * v2 + s4.w * v3;
    }
  }
#pragma unroll
  for (int a = 0; a < 8; ++a) atomicAdd(&att1[(size_t)bh * 1024 + a * 128 + d], acc[a]);
}

// ---------------- zero fill ----------------
__global__ __launch_bounds__(256) void zero_f(float* __restrict__ p, int total) {
  const int idx = blockIdx.x * 256 + threadIdx.x;
  if (idx < total) p[idx] = 0.f;
}

// ---------------- bias init for atomic split-K GEMMs ----------------
__global__ __launch_bounds__(256) void init_bias(float* __restrict__ C,
                                                 const float* __restrict__ bias,
                                                 int N, int permuted, int total) {
  const int idx = blockIdx.x * 256 + threadIdx.x;
  if (idx >= total) return;
  const int row = idx / N, col = idx - row * N;
  float v;
  if (!permuted)
    v = bias[col];
  else
    v = bias[(row & 7) * 512 + (col & 511)];
  C[idx] = v;
}

// ---------------- small-M (64) f32 GEMM, split-K with atomic accumulate ----------------
__global__ __launch_bounds__(256) void mlp_gemm(const float* __restrict__ A,
                                                const float* __restrict__ W,
                                                float* __restrict__ C,
                                                int K, int N, int reluA, int permOut) {
  __shared__ float sAT[64][68];
  __shared__ float sW[64][68];
  const int tid = threadIdx.x;
  const int n0 = blockIdx.x * 64;
  const int tx = tid & 15, ty = tid >> 4;
  float acc[4][4] = {};
  const int kbeg = blockIdx.y * 512, kend = kbeg + 512;
  for (int k0 = kbeg; k0 < kend; k0 += 64) {
    for (int i = tid; i < 4096; i += 256) {
      const int m = i >> 6, kk = i & 63;
      const float a = A[(size_t)m * K + k0 + kk];
      sAT[kk][m] = reluA ? fmaxf(a, 0.f) : a;
      sW[m][kk] = W[(size_t)(k0 + m) * N + n0 + kk];
    }
    __syncthreads();
#pragma unroll 4
    for (int k = 0; k < 64; ++k) {
      const float4 av = *(const float4*)&sAT[k][ty * 4];
      const float4 wv = *(const float4*)&sW[k][tx * 4];
      const float aa[4] = {av.x, av.y, av.z, av.w};
      const float ww[4] = {wv.x, wv.y, wv.z, wv.w};
#pragma unroll
      for (int i = 0; i < 4; ++i)
#pragma unroll
        for (int j = 0; j < 4; ++j) acc[i][j] += aa[i] * ww[j];
    }
    __syncthreads();
  }
#pragma unroll
  for (int i = 0; i < 4; ++i)
#pragma unroll
    for (int j = 0; j < 4; ++j) {
      const int row = ty * 4 + i;
      const int col = n0 + tx * 4 + j;
      size_t idx;
      if (!permOut) {
        idx = (size_t)row * N + col;
      } else {
        const int bb = row >> 3, hh = row & 7, a2 = col >> 9, jj = col & 511;
        idx = (size_t)(bb * 8 + a2) * 4096 + hh * 512 + jj;
      }
      atomicAdd(&C[idx], acc[i][j]);
    }
}

// ---------------- attention 2: 2048 queries vs 8 anchor keys + PV ----------------
__global__ __launch_bounds__(256) void attn2_kernel(const u16* __restrict__ qkv,
                                                    const float* __restrict__ kk,
                                                    const float* __restrict__ onet,
                                                    u16* __restrict__ y) {
  __shared__ float kkl[8][128];
  __shared__ float ovl[8][128];
  const int tid = threadIdx.x;
  const int chunk = blockIdx.x & 7, bh = blockIdx.x >> 3;
  const int b = bh >> 3, h = bh & 7;
  for (int i = tid; i < 1024; i += 256) {
    const int a = i >> 7, d = i & 127;
    kkl[a][d] = kk[(size_t)(b * 8 + a) * 1024 + h * 128 + d];
    ovl[a][d] = onet[(size_t)(b * 8 + a) * 1024 + h * 128 + d];
  }
  __syncthreads();
  const int n = chunk * 256 + tid;
  const u16* qp = qkv + (size_t)(b * 2048 + n) * 3072 + h * 128;
  float dots[8] = {0, 0, 0, 0, 0, 0, 0, 0};
#pragma unroll 4
  for (int dd = 0; dd < 128; dd += 4) {
    const ushort4 q4 = *(const ushort4*)(qp + dd);
    const float q0 = bf2f(q4.x), q1 = bf2f(q4.y), q2 = bf2f(q4.z), q3 = bf2f(q4.w);
#pragma unroll
    for (int a = 0; a < 8; ++a) {
      const float4 k4 = *(const float4*)&kkl[a][dd];
      dots[a] += k4.x * q0 + k4.y * q1 + k4.z * q2 + k4.w * q3;
    }
  }
  const float scale = 0.0883883476483184f;
  float mx = -1e30f;
#pragma unroll
  for (int a = 0; a < 8; ++a) {
    dots[a] *= scale;
    mx = fmaxf(mx, dots[a]);
  }
  float p[8];
  float sum = 0.f;
#pragma unroll
  for (int a = 0; a < 8; ++a) {
    p[a] = __expf(dots[a] - mx);
    sum += p[a];
  }
  const float inv = 1.f / sum;
#pragma unroll
  for (int a = 0; a < 8; ++a) p[a] *= inv;
  u16* yp = y + (size_t)(b * 2048 + n) * 1024 + h * 128;
#pragma unroll 4
  for (int dd = 0; dd < 128; dd += 4) {
    float a0 = 0, a1 = 0, a2 = 0, a3 = 0;
#pragma unroll
    for (int a = 0; a < 8; ++a) {
      const float4 o4 = *(const float4*)&ovl[a][dd];
      a0 += p[a] * o4.x;
      a1 += p[a] * o4.y;
      a2 += p[a] * o4.z;
      a3 += p[a] * o4.w;
    }
    ushort4 o;
    o.x = f2bf(a0);
    o.y = f2bf(a1);
    o.z = f2bf(a2);
    o.w = f2bf(a3);
    *(ushort4*)(yp + dd) = o;
  }
}

extern "C" void kernel_launch(void* const* d_in, const int* in_sizes, int n_in,
                              void* d_out, int out_size, void* d_ws, size_t ws_size,
                              hipStream_t stream) {
  const float* inputs = (const float*)d_in[0];
  const float* ln_g = (const float*)d_in[1];
  const float* ln_b = (const float*)d_in[2];
  const float* q_anchor = (const float*)d_in[3];
  const float* W_qkv = (const float*)d_in[4];
  const float* b_qkv = (const float*)d_in[5];
  const float* W_an = (const float*)d_in[6];
  const float* b_an = (const float*)d_in[7];
  const float* W_n1 = (const float*)d_in[8];
  const float* b_n1 = (const float*)d_in[9];
  const float* W_n2 = (const float*)d_in[10];
  const float* b_n2 = (const float*)d_in[11];
  const float* W_n3 = (const float*)d_in[12];
  const float* b_n3 = (const float*)d_in[13];
  const float* W_k = (const float*)d_in[14];
  const float* b_k = (const float*)d_in[15];
  const float* W_o = (const float*)d_in[16];
  const float* b_o = (const float*)d_in[17];
  float* out = (float*)d_out;

  char* ws = (char*)d_ws;
  u16* qkv = (u16*)(ws);                                   // 16384*3072 bf16 = 96 MB
  u16* xbf = (u16*)(ws + 100663296);                       // 16384*1024 bf16 (x, later y)
  float* S = (float*)(ws + 100663296);                     // attn1 scores 4 MB (overlays dead x)
  u16* WqkvT = (u16*)(ws + 100663296 + 33554432);          // 3072*1024 bf16
  u16* WoT = (u16*)(ws + 140509184);                       // 1024*1024 bf16
  float* att1 = (float*)(ws + 142606336);                  // 64*1024
  float* anp = (float*)(ws + 142868480);                   // 64*4096
  float* h1 = (float*)(ws + 143917056);                    // 64*1024
  float* h2 = (float*)(ws + 144179200);                    // 64*4096
  float* onet = (float*)(ws + 145227776);                  // 64*1024
  float* kkb = (float*)(ws + 145489920);                   // 64*1024

  // 1) LayerNorm -> x bf16
  ln_kernel<<<16384, 256, 0, stream>>>(inputs, ln_g, ln_b, xbf);
  // 2) weight transpose/convert
  transpose_bf16<<<dim3(32, 96), 256, 0, stream>>>(W_qkv, WqkvT, 1024, 3072);
  transpose_bf16<<<dim3(32, 32), 256, 0, stream>>>(W_o, WoT, 1024, 1024);
  // 3) QKV GEMM -> qkv bf16  (x dead afterwards; S overlays it)
  gemm_bf16<0><<<dim3(128, 24), 256, 0, stream>>>(xbf, WqkvT, b_qkv, nullptr, qkv, nullptr,
                                                  16384, 3072, 1024);
  // 4) anchor attention: scores -> softmax -> partial PV (512-block parallelism)
  zero_f<<<256, 256, 0, stream>>>(att1, 64 * 1024);
  attn1_scores<<<512, 256, 0, stream>>>(qkv, q_anchor, S);
  attn1_softmax<<<512, 256, 0, stream>>>(S);
  attn1_pv<<<512, 256, 0, stream>>>(qkv, S, att1);
  // 5) MLP chain
  init_bias<<<1024, 256, 0, stream>>>(anp, b_an, 4096, 1, 64 * 4096);
  init_bias<<<256, 256, 0, stream>>>(h1, b_n1, 1024, 0, 64 * 1024);
  init_bias<<<1024, 256, 0, stream>>>(h2, b_n2, 4096, 0, 64 * 4096);
  init_bias<<<256, 256, 0, stream>>>(onet, b_n3, 1024, 0, 64 * 1024);
  init_bias<<<256, 256, 0, stream>>>(kkb, b_k, 1024, 0, 64 * 1024);
  mlp_gemm<<<dim3(64, 2), 256, 0, stream>>>(att1, W_an, anp, 1024, 4096, 0, 1);
  mlp_gemm<<<dim3(16, 8), 256, 0, stream>>>(anp, W_n1, h1, 4096, 1024, 1, 0);
  mlp_gemm<<<dim3(64, 2), 256, 0, stream>>>(h1, W_n2, h2, 1024, 4096, 0, 0);
  mlp_gemm<<<dim3(16, 8), 256, 0, stream>>>(h2, W_n3, onet, 4096, 1024, 1, 0);
  mlp_gemm<<<dim3(16, 2), 256, 0, stream>>>(onet, W_k, kkb, 1024, 1024, 0, 0);
  // 6) query attention over 8 anchors -> y bf16 (reuses xbf buffer)
  attn2_kernel<<<512, 256, 0, stream>>>(qkv, kkb, onet, xbf);
  // 7) output GEMM + bias + residual -> d_out f32
  gemm_bf16<1><<<dim3(128, 8), 256, 0, stream>>>(xbf, WoT, b_o, inputs, nullptr, out,
                                                 16384, 1024, 1024);
}

// Round 3
// 715.837 us; speedup vs baseline: 1.2872x; 1.1462x over previous
//
#include <hip/hip_runtime.h>
#include <cstdint>
#include <cstddef>

typedef unsigned short u16;
typedef __attribute__((ext_vector_type(8))) short short8;
typedef __attribute__((ext_vector_type(4))) float floatx4;

__device__ __forceinline__ u16 f2bf(float f) {
  unsigned u = __float_as_uint(f);
  u += 0x7fffu + ((u >> 16) & 1u);
  return (u16)(u >> 16);
}
__device__ __forceinline__ float bf2f(u16 s) {
  return __uint_as_float(((unsigned)s) << 16);
}

// ---------------- LayerNorm (f32 in) -> bf16 x ----------------
__global__ __launch_bounds__(256) void ln_kernel(const float* __restrict__ x,
                                                 const float* __restrict__ g,
                                                 const float* __restrict__ bta,
                                                 u16* __restrict__ out) {
  const int row = blockIdx.x;
  const int tid = threadIdx.x;
  const float4 v = ((const float4*)(x + (size_t)row * 1024))[tid];
  float s = v.x + v.y + v.z + v.w;
#pragma unroll
  for (int o = 32; o > 0; o >>= 1) s += __shfl_down(s, o);
  __shared__ float red[4], red2[4];
  const int wv = tid >> 6, ln = tid & 63;
  if (ln == 0) red[wv] = s;
  __syncthreads();
  const float mean = (red[0] + red[1] + red[2] + red[3]) * (1.0f / 1024.0f);
  const float dx = v.x - mean, dy = v.y - mean, dz = v.z - mean, dw = v.w - mean;
  float s2 = dx * dx + dy * dy + dz * dz + dw * dw;
#pragma unroll
  for (int o = 32; o > 0; o >>= 1) s2 += __shfl_down(s2, o);
  if (ln == 0) red2[wv] = s2;
  __syncthreads();
  const float var = (red2[0] + red2[1] + red2[2] + red2[3]) * (1.0f / 1024.0f);
  const float rstd = rsqrtf(var + 1e-6f);
  const float4 gg = ((const float4*)g)[tid];
  const float4 bb = ((const float4*)bta)[tid];
  ushort4 o4;
  o4.x = f2bf(dx * rstd * gg.x + bb.x);
  o4.y = f2bf(dy * rstd * gg.y + bb.y);
  o4.z = f2bf(dz * rstd * gg.z + bb.z);
  o4.w = f2bf(dw * rstd * gg.w + bb.w);
  ((ushort4*)(out + (size_t)row * 1024))[tid] = o4;
}

// ---------------- W (KxN f32) -> WT (NxK bf16) ----------------
__global__ __launch_bounds__(256) void transpose_bf16(const float* __restrict__ W,
                                                      u16* __restrict__ WT,
                                                      int K, int N) {
  __shared__ float t[32][33];
  const int kb = blockIdx.x * 32, nb = blockIdx.y * 32;
  const int tx = threadIdx.x & 31, ty = threadIdx.x >> 5;
#pragma unroll
  for (int i = ty; i < 32; i += 8) t[i][tx] = W[(size_t)(kb + i) * N + nb + tx];
  __syncthreads();
#pragma unroll
  for (int i = ty; i < 32; i += 8) WT[(size_t)(nb + i) * K + kb + tx] = f2bf(t[tx][i]);
}

// ---------------- big bf16 MFMA GEMM: C = A(MxK) * BT(NxK)^T + bias ----------------
template <int EPI>
__global__ __launch_bounds__(256) void gemm_bf16(const u16* __restrict__ A,
                                                 const u16* __restrict__ BT,
                                                 const float* __restrict__ bias,
                                                 const float* __restrict__ extra,
                                                 u16* __restrict__ outB,
                                                 float* __restrict__ outF,
                                                 int M, int N, int K) {
  __shared__ u16 sA[128 * 64];
  __shared__ u16 sB[128 * 64];
  const int tid = threadIdx.x;
  const int wave = tid >> 6, lane = tid & 63;
  const int m0 = blockIdx.x * 128, n0 = blockIdx.y * 128;
  const int wm = (wave >> 1) * 64, wn = (wave & 1) * 64;

  floatx4 acc[4][4];
  const floatx4 zero = {0.f, 0.f, 0.f, 0.f};
#pragma unroll
  for (int i = 0; i < 4; ++i)
#pragma unroll
    for (int j = 0; j < 4; ++j) acc[i][j] = zero;

  const int srow = wave * 32 + (lane >> 3);
  const int sslot = lane & 7;

  for (int kt = 0; kt < K; kt += 64) {
#pragma unroll
    for (int i = 0; i < 4; ++i) {
      const int rl = srow + i * 8;
      const int gA = sslot ^ (rl & 7);
      const u16* ga = A + (size_t)(m0 + rl) * K + kt + gA * 8;
      u16* la = sA + (wave * 32 + i * 8) * 64;
      __builtin_amdgcn_global_load_lds((const __attribute__((address_space(1))) void*)ga,
                                       (__attribute__((address_space(3))) void*)la, 16, 0, 0);
    }
#pragma unroll
    for (int i = 0; i < 4; ++i) {
      const int rl = srow + i * 8;
      const int gB = sslot ^ (rl & 7);
      const u16* gb = BT + (size_t)(n0 + rl) * K + kt + gB * 8;
      u16* lb = sB + (wave * 32 + i * 8) * 64;
      __builtin_amdgcn_global_load_lds((const __attribute__((address_space(1))) void*)gb,
                                       (__attribute__((address_space(3))) void*)lb, 16, 0, 0);
    }
    __syncthreads();
    const int fr = lane & 15, fq = lane >> 4;
#pragma unroll
    for (int ks = 0; ks < 2; ++ks) {
      short8 af[4], bfr[4];
#pragma unroll
      for (int i = 0; i < 4; ++i) {
        const int rl = wm + i * 16 + fr;
        const int g = ks * 4 + fq;
        af[i] = *(const short8*)(sA + rl * 64 + (g ^ (rl & 7)) * 8);
      }
#pragma unroll
      for (int j = 0; j < 4; ++j) {
        const int rl = wn + j * 16 + fr;
        const int g = ks * 4 + fq;
        bfr[j] = *(const short8*)(sB + rl * 64 + (g ^ (rl & 7)) * 8);
      }
#pragma unroll
      for (int i = 0; i < 4; ++i)
#pragma unroll
        for (int j = 0; j < 4; ++j)
          acc[i][j] = __builtin_amdgcn_mfma_f32_16x16x32_bf16(af[i], bfr[j], acc[i][j], 0, 0, 0);
    }
    __syncthreads();
  }

  const int fr = lane & 15, fq = lane >> 4;
#pragma unroll
  for (int i = 0; i < 4; ++i)
#pragma unroll
    for (int j = 0; j < 4; ++j)
#pragma unroll
      for (int r = 0; r < 4; ++r) {
        const int m = m0 + wm + i * 16 + fq * 4 + r;
        const int n = n0 + wn + j * 16 + fr;
        const float v = acc[i][j][r] + bias[n];
        if (EPI == 0)
          outB[(size_t)m * N + n] = f2bf(v);
        else
          outF[(size_t)m * N + n] = v + extra[(size_t)m * N + n];
      }
}

// ---------------- attn1 stage A: scores S[bh][a][n] ----------------
__global__ __launch_bounds__(256) void attn1_scores(const u16* __restrict__ qkv,
                                                    const float* __restrict__ q_anchor,
                                                    float* __restrict__ S) {
  __shared__ float qa[8][128];
  const int tid = threadIdx.x;
  const int chunk = blockIdx.x & 7, bh = blockIdx.x >> 3;
  const int b = bh >> 3, h = bh & 7;
  for (int i = tid; i < 1024; i += 256) qa[i >> 7][i & 127] = q_anchor[h * 1024 + i];
  __syncthreads();
  const float scale = 0.0883883476483184f;
  const int n = chunk * 256 + tid;
  const u16* kp = qkv + (size_t)(b * 2048 + n) * 3072 + 1024 + h * 128;
  float dots[8] = {0, 0, 0, 0, 0, 0, 0, 0};
#pragma unroll 8
  for (int dd = 0; dd < 128; dd += 4) {
    const ushort4 k4 = *(const ushort4*)(kp + dd);
    const float k0 = bf2f(k4.x), k1 = bf2f(k4.y), k2 = bf2f(k4.z), k3 = bf2f(k4.w);
#pragma unroll
    for (int a = 0; a < 8; ++a) {
      const float4 q4 = *(const float4*)&qa[a][dd];
      dots[a] += q4.x * k0 + q4.y * k1 + q4.z * k2 + q4.w * k3;
    }
  }
#pragma unroll
  for (int a = 0; a < 8; ++a) S[((size_t)(bh * 8 + a)) * 2048 + n] = dots[a] * scale;
}

// ---------------- attn1 stage B: row softmax over 2048, in place ----------------
__global__ __launch_bounds__(256) void attn1_softmax(float* __restrict__ S) {
  const int row = blockIdx.x;
  const int tid = threadIdx.x;
  float* Sp = S + (size_t)row * 2048;
  float4 v0 = ((const float4*)Sp)[tid * 2];
  float4 v1 = ((const float4*)Sp)[tid * 2 + 1];
  float mx = fmaxf(fmaxf(fmaxf(v0.x, v0.y), fmaxf(v0.z, v0.w)),
                   fmaxf(fmaxf(v1.x, v1.y), fmaxf(v1.z, v1.w)));
#pragma unroll
  for (int o = 32; o > 0; o >>= 1) mx = fmaxf(mx, __shfl_xor(mx, o));
  __shared__ float red[4];
  const int wv = tid >> 6, ln = tid & 63;
  if (ln == 0) red[wv] = mx;
  __syncthreads();
  mx = fmaxf(fmaxf(red[0], red[1]), fmaxf(red[2], red[3]));
  v0.x = __expf(v0.x - mx); v0.y = __expf(v0.y - mx);
  v0.z = __expf(v0.z - mx); v0.w = __expf(v0.w - mx);
  v1.x = __expf(v1.x - mx); v1.y = __expf(v1.y - mx);
  v1.z = __expf(v1.z - mx); v1.w = __expf(v1.w - mx);
  float sum = v0.x + v0.y + v0.z + v0.w + v1.x + v1.y + v1.z + v1.w;
#pragma unroll
  for (int o = 32; o > 0; o >>= 1) sum += __shfl_xor(sum, o);
  __shared__ float red2[4];
  if (ln == 0) red2[wv] = sum;
  __syncthreads();
  const float inv = 1.f / (red2[0] + red2[1] + red2[2] + red2[3]);
  v0.x *= inv; v0.y *= inv; v0.z *= inv; v0.w *= inv;
  v1.x *= inv; v1.y *= inv; v1.z *= inv; v1.w *= inv;
  ((float4*)Sp)[tid * 2] = v0;
  ((float4*)Sp)[tid * 2 + 1] = v1;
}

// ---------------- attn1 stage C: partial PV, atomic accumulate ----------------
__global__ __launch_bounds__(256) void attn1_pv(const u16* __restrict__ qkv,
                                                const float* __restrict__ S,
                                                float* __restrict__ att1) {
  __shared__ float P[8][256];
  const int tid = threadIdx.x;
  const int chunk = blockIdx.x & 7, bh = blockIdx.x >> 3;
  const int b = bh >> 3, h = bh & 7;
  for (int i = tid; i < 2048; i += 256) {
    const int a = i >> 8, n = i & 255;
    P[a][n] = S[((size_t)(bh * 8 + a)) * 2048 + chunk * 256 + n];
  }
  __syncthreads();
  const int d = tid & 127, half = tid >> 7;
  const int nbase = chunk * 256 + half * 128;
  const u16* vp = qkv + (size_t)(b * 2048 + nbase) * 3072 + 2048 + h * 128 + d;
  float acc[8] = {0.f};
  for (int n = 0; n < 128; n += 4) {
    const float v0 = bf2f(vp[(size_t)n * 3072]);
    const float v1 = bf2f(vp[(size_t)(n + 1) * 3072]);
    const float v2 = bf2f(vp[(size_t)(n + 2) * 3072]);
    const float v3 = bf2f(vp[(size_t)(n + 3) * 3072]);
#pragma unroll
    for (int a = 0; a < 8; ++a) {
      const float4 s4 = *(const float4*)&P[a][half * 128 + n];
      acc[a] += s4.x * v0 + s4.y * v1 + s4.z * v2 + s4.w * v3;
    }
  }
#pragma unroll
  for (int a = 0; a < 8; ++a) atomicAdd(&att1[(size_t)bh * 1024 + a * 128 + d], acc[a]);
}

// ---------------- zero fill ----------------
__global__ __launch_bounds__(256) void zero_f(float* __restrict__ p, int total) {
  const int idx = blockIdx.x * 256 + threadIdx.x;
  if (idx < total) p[idx] = 0.f;
}

// ---------------- MLP streaming GEMM: part[split][64][N] = A[64][Kc] @ W[Kc][N] ----------------
// Block: 64-col n-slice x KC k-chunk. 4 waves; wave w computes m in [w*16, w*16+16).
// W read coalesced (one dword per lane per k), exactly once grid-wide. A staged in LDS,
// read as wave-uniform broadcast float4 (conflict-free).
__global__ __launch_bounds__(256) void mlp_gemm2(const float* __restrict__ A,
                                                 const float* __restrict__ W,
                                                 float* __restrict__ part,
                                                 int K, int N, int KC) {
  __shared__ float sA[64][64];
  const int tid = threadIdx.x;
  const int lane = tid & 63, wave = tid >> 6;
  const int wm = wave * 16;
  const int n0 = blockIdx.x * 64;
  const int kbeg = blockIdx.y * KC;
  float acc[16];
#pragma unroll
  for (int m = 0; m < 16; ++m) acc[m] = 0.f;

  for (int kc = 0; kc < KC; kc += 64) {
    const int kbase = kbeg + kc;
    __syncthreads();
    for (int i = tid; i < 4096; i += 256)
      sA[i >> 6][i & 63] = A[(size_t)(i >> 6) * K + kbase + (i & 63)];
    __syncthreads();
#pragma unroll 2
    for (int kq = 0; kq < 16; ++kq) {
      const float* wp = W + (size_t)(kbase + kq * 4) * N + n0 + lane;
      const float w0 = wp[0];
      const float w1 = wp[N];
      const float w2 = wp[2 * (size_t)N];
      const float w3 = wp[3 * (size_t)N];
#pragma unroll
      for (int m = 0; m < 16; ++m) {
        const float4 a4 = *(const float4*)&sA[wm + m][kq * 4];
        acc[m] = fmaf(a4.w, w3, fmaf(a4.z, w2, fmaf(a4.y, w1, fmaf(a4.x, w0, acc[m]))));
      }
    }
  }
#pragma unroll
  for (int m = 0; m < 16; ++m)
    part[((size_t)blockIdx.y * 64 + wm + m) * N + n0 + lane] = acc[m];
}

// ---------------- MLP reduce: out = [relu](sum_s part + bias), optional an-permute ----------------
__global__ __launch_bounds__(256) void mlp_reduce(const float* __restrict__ part,
                                                  const float* __restrict__ bias,
                                                  float* __restrict__ out,
                                                  int N, int nsplit, int relu, int perm) {
  const int idx = blockIdx.x * 256 + threadIdx.x;
  const int e = idx * 4;
  if (e >= 64 * N) return;
  const int row = e / N, col = e - row * N;
  float4 acc = *(const float4*)&bias[col];
  for (int s = 0; s < nsplit; ++s) {
    const float4 p = *(const float4*)&part[((size_t)s * 64 + row) * N + col];
    acc.x += p.x; acc.y += p.y; acc.z += p.z; acc.w += p.w;
  }
  if (relu) {
    acc.x = fmaxf(acc.x, 0.f); acc.y = fmaxf(acc.y, 0.f);
    acc.z = fmaxf(acc.z, 0.f); acc.w = fmaxf(acc.w, 0.f);
  }
  size_t oidx;
  if (!perm) {
    oidx = (size_t)row * N + col;
  } else {
    const int b = row >> 3, h = row & 7;
    oidx = (size_t)(b * 8 + (col >> 9)) * 4096 + h * 512 + (col & 511);
  }
  *(float4*)&out[oidx] = acc;
}

// ---------------- attention 2: 2048 queries vs 8 anchor keys + PV ----------------
__global__ __launch_bounds__(256) void attn2_kernel(const u16* __restrict__ qkv,
                                                    const float* __restrict__ kk,
                                                    const float* __restrict__ onet,
                                                    u16* __restrict__ y) {
  __shared__ float kkl[8][128];
  __shared__ float ovl[8][128];
  const int tid = threadIdx.x;
  const int chunk = blockIdx.x & 7, bh = blockIdx.x >> 3;
  const int b = bh >> 3, h = bh & 7;
  for (int i = tid; i < 1024; i += 256) {
    const int a = i >> 7, d = i & 127;
    kkl[a][d] = kk[(size_t)(b * 8 + a) * 1024 + h * 128 + d];
    ovl[a][d] = onet[(size_t)(b * 8 + a) * 1024 + h * 128 + d];
  }
  __syncthreads();
  const int n = chunk * 256 + tid;
  const u16* qp = qkv + (size_t)(b * 2048 + n) * 3072 + h * 128;
  float dots[8] = {0, 0, 0, 0, 0, 0, 0, 0};
#pragma unroll 4
  for (int dd = 0; dd < 128; dd += 4) {
    const ushort4 q4 = *(const ushort4*)(qp + dd);
    const float q0 = bf2f(q4.x), q1 = bf2f(q4.y), q2 = bf2f(q4.z), q3 = bf2f(q4.w);
#pragma unroll
    for (int a = 0; a < 8; ++a) {
      const float4 k4 = *(const float4*)&kkl[a][dd];
      dots[a] += k4.x * q0 + k4.y * q1 + k4.z * q2 + k4.w * q3;
    }
  }
  const float scale = 0.0883883476483184f;
  float mx = -1e30f;
#pragma unroll
  for (int a = 0; a < 8; ++a) {
    dots[a] *= scale;
    mx = fmaxf(mx, dots[a]);
  }
  float p[8];
  float sum = 0.f;
#pragma unroll
  for (int a = 0; a < 8; ++a) {
    p[a] = __expf(dots[a] - mx);
    sum += p[a];
  }
  const float inv = 1.f / sum;
#pragma unroll
  for (int a = 0; a < 8; ++a) p[a] *= inv;
  u16* yp = y + (size_t)(b * 2048 + n) * 1024 + h * 128;
#pragma unroll 4
  for (int dd = 0; dd < 128; dd += 4) {
    float a0 = 0, a1 = 0, a2 = 0, a3 = 0;
#pragma unroll
    for (int a = 0; a < 8; ++a) {
      const float4 o4 = *(const float4*)&ovl[a][dd];
      a0 += p[a] * o4.x;
      a1 += p[a] * o4.y;
      a2 += p[a] * o4.z;
      a3 += p[a] * o4.w;
    }
    ushort4 o;
    o.x = f2bf(a0);
    o.y = f2bf(a1);
    o.z = f2bf(a2);
    o.w = f2bf(a3);
    *(ushort4*)(yp + dd) = o;
  }
}

extern "C" void kernel_launch(void* const* d_in, const int* in_sizes, int n_in,
                              void* d_out, int out_size, void* d_ws, size_t ws_size,
                              hipStream_t stream) {
  const float* inputs = (const float*)d_in[0];
  const float* ln_g = (const float*)d_in[1];
  const float* ln_b = (const float*)d_in[2];
  const float* q_anchor = (const float*)d_in[3];
  const float* W_qkv = (const float*)d_in[4];
  const float* b_qkv = (const float*)d_in[5];
  const float* W_an = (const float*)d_in[6];
  const float* b_an = (const float*)d_in[7];
  const float* W_n1 = (const float*)d_in[8];
  const float* b_n1 = (const float*)d_in[9];
  const float* W_n2 = (const float*)d_in[10];
  const float* b_n2 = (const float*)d_in[11];
  const float* W_n3 = (const float*)d_in[12];
  const float* b_n3 = (const float*)d_in[13];
  const float* W_k = (const float*)d_in[14];
  const float* b_k = (const float*)d_in[15];
  const float* W_o = (const float*)d_in[16];
  const float* b_o = (const float*)d_in[17];
  float* out = (float*)d_out;

  char* ws = (char*)d_ws;
  u16* qkv = (u16*)(ws);                                   // 16384*3072 bf16 = 96 MB
  u16* xbf = (u16*)(ws + 100663296);                       // 16384*1024 bf16 (x, later y)
  float* S = (float*)(ws + 100663296);                     // attn1 scores 4 MB (overlays dead x)
  float* part = (float*)(ws + 100663296);                  // MLP partials 8 MB (same dead region)
  u16* WqkvT = (u16*)(ws + 100663296 + 33554432);          // 3072*1024 bf16
  u16* WoT = (u16*)(ws + 140509184);                       // 1024*1024 bf16
  float* att1 = (float*)(ws + 142606336);                  // 64*1024
  float* anp = (float*)(ws + 142868480);                   // 64*4096
  float* h1 = (float*)(ws + 143917056);                    // 64*1024
  float* h2 = (float*)(ws + 144179200);                    // 64*4096
  float* onet = (float*)(ws + 145227776);                  // 64*1024
  float* kkb = (float*)(ws + 145489920);                   // 64*1024

  // 1) LayerNorm -> x bf16
  ln_kernel<<<16384, 256, 0, stream>>>(inputs, ln_g, ln_b, xbf);
  // 2) weight transpose/convert
  transpose_bf16<<<dim3(32, 96), 256, 0, stream>>>(W_qkv, WqkvT, 1024, 3072);
  transpose_bf16<<<dim3(32, 32), 256, 0, stream>>>(W_o, WoT, 1024, 1024);
  // 3) QKV GEMM -> qkv bf16  (x dead afterwards; S/part overlay it)
  gemm_bf16<0><<<dim3(128, 24), 256, 0, stream>>>(xbf, WqkvT, b_qkv, nullptr, qkv, nullptr,
                                                  16384, 3072, 1024);
  // 4) anchor attention: scores -> softmax -> partial PV
  zero_f<<<256, 256, 0, stream>>>(att1, 64 * 1024);
  attn1_scores<<<512, 256, 0, stream>>>(qkv, q_anchor, S);
  attn1_softmax<<<512, 256, 0, stream>>>(S);
  attn1_pv<<<512, 256, 0, stream>>>(qkv, S, att1);
  // 5) MLP chain: streaming GEMM -> fused reduce(bias/relu/permute)
  mlp_gemm2<<<dim3(64, 8), 256, 0, stream>>>(att1, W_an, part, 1024, 4096, 128);
  mlp_reduce<<<256, 256, 0, stream>>>(part, b_an, anp, 4096, 8, 1, 1);
  mlp_gemm2<<<dim3(16, 32), 256, 0, stream>>>(anp, W_n1, part, 4096, 1024, 128);
  mlp_reduce<<<64, 256, 0, stream>>>(part, b_n1, h1, 1024, 32, 0, 0);
  mlp_gemm2<<<dim3(64, 8), 256, 0, stream>>>(h1, W_n2, part, 1024, 4096, 128);
  mlp_reduce<<<256, 256, 0, stream>>>(part, b_n2, h2, 4096, 8, 1, 0);
  mlp_gemm2<<<dim3(16, 32), 256, 0, stream>>>(h2, W_n3, part, 4096, 1024, 128);
  mlp_reduce<<<64, 256, 0, stream>>>(part, b_n3, onet, 1024, 32, 0, 0);
  mlp_gemm2<<<dim3(16, 16), 256, 0, stream>>>(onet, W_k, part, 1024, 1024, 64);
  mlp_reduce<<<64, 256, 0, stream>>>(part, b_k, kkb, 1024, 16, 0, 0);
  // 6) query attention over 8 anchors -> y bf16 (reuses xbf buffer; part now dead)
  attn2_kernel<<<512, 256, 0, stream>>>(qkv, kkb, onet, xbf);
  // 7) output GEMM + bias + residual -> d_out f32
  gemm_bf16<1><<<dim3(128, 8), 256, 0, stream>>>(xbf, WoT, b_o, inputs, nullptr, out,
                                                 16384, 1024, 1024);
}

// Round 4
// 639.451 us; speedup vs baseline: 1.4410x; 1.1195x over previous
//
#include <hip/hip_runtime.h>
#include <cstdint>
#include <cstddef>

typedef unsigned short u16;
typedef __attribute__((ext_vector_type(8))) short short8;
typedef __attribute__((ext_vector_type(4))) float floatx4;

__device__ __forceinline__ u16 f2bf(float f) {
  unsigned u = __float_as_uint(f);
  u += 0x7fffu + ((u >> 16) & 1u);
  return (u16)(u >> 16);
}
__device__ __forceinline__ float bf2f(u16 s) {
  return __uint_as_float(((unsigned)s) << 16);
}

// ---------------- LayerNorm (f32 in) -> bf16 x ----------------
__global__ __launch_bounds__(256) void ln_kernel(const float* __restrict__ x,
                                                 const float* __restrict__ g,
                                                 const float* __restrict__ bta,
                                                 u16* __restrict__ out) {
  const int row = blockIdx.x;
  const int tid = threadIdx.x;
  const float4 v = ((const float4*)(x + (size_t)row * 1024))[tid];
  float s = v.x + v.y + v.z + v.w;
#pragma unroll
  for (int o = 32; o > 0; o >>= 1) s += __shfl_down(s, o);
  __shared__ float red[4], red2[4];
  const int wv = tid >> 6, ln = tid & 63;
  if (ln == 0) red[wv] = s;
  __syncthreads();
  const float mean = (red[0] + red[1] + red[2] + red[3]) * (1.0f / 1024.0f);
  const float dx = v.x - mean, dy = v.y - mean, dz = v.z - mean, dw = v.w - mean;
  float s2 = dx * dx + dy * dy + dz * dz + dw * dw;
#pragma unroll
  for (int o = 32; o > 0; o >>= 1) s2 += __shfl_down(s2, o);
  if (ln == 0) red2[wv] = s2;
  __syncthreads();
  const float var = (red2[0] + red2[1] + red2[2] + red2[3]) * (1.0f / 1024.0f);
  const float rstd = rsqrtf(var + 1e-6f);
  const float4 gg = ((const float4*)g)[tid];
  const float4 bb = ((const float4*)bta)[tid];
  ushort4 o4;
  o4.x = f2bf(dx * rstd * gg.x + bb.x);
  o4.y = f2bf(dy * rstd * gg.y + bb.y);
  o4.z = f2bf(dz * rstd * gg.z + bb.z);
  o4.w = f2bf(dw * rstd * gg.w + bb.w);
  ((ushort4*)(out + (size_t)row * 1024))[tid] = o4;
}

// ---------------- W (KxN f32) -> WT (NxK bf16) ----------------
__global__ __launch_bounds__(256) void transpose_bf16(const float* __restrict__ W,
                                                      u16* __restrict__ WT,
                                                      int K, int N) {
  __shared__ float t[32][33];
  const int kb = blockIdx.x * 32, nb = blockIdx.y * 32;
  const int tx = threadIdx.x & 31, ty = threadIdx.x >> 5;
#pragma unroll
  for (int i = ty; i < 32; i += 8) t[i][tx] = W[(size_t)(kb + i) * N + nb + tx];
  __syncthreads();
#pragma unroll
  for (int i = ty; i < 32; i += 8) WT[(size_t)(nb + i) * K + kb + tx] = f2bf(t[tx][i]);
}

// ---------------- big bf16 MFMA GEMM: C = A(MxK) * BT(NxK)^T + bias ----------------
template <int EPI>
__global__ __launch_bounds__(256) void gemm_bf16(const u16* __restrict__ A,
                                                 const u16* __restrict__ BT,
                                                 const float* __restrict__ bias,
                                                 const float* __restrict__ extra,
                                                 u16* __restrict__ outB,
                                                 float* __restrict__ outF,
                                                 int M, int N, int K) {
  __shared__ u16 sA[128 * 64];
  __shared__ u16 sB[128 * 64];
  const int tid = threadIdx.x;
  const int wave = tid >> 6, lane = tid & 63;
  const int m0 = blockIdx.x * 128, n0 = blockIdx.y * 128;
  const int wm = (wave >> 1) * 64, wn = (wave & 1) * 64;

  floatx4 acc[4][4];
  const floatx4 zero = {0.f, 0.f, 0.f, 0.f};
#pragma unroll
  for (int i = 0; i < 4; ++i)
#pragma unroll
    for (int j = 0; j < 4; ++j) acc[i][j] = zero;

  const int srow = wave * 32 + (lane >> 3);
  const int sslot = lane & 7;

  for (int kt = 0; kt < K; kt += 64) {
#pragma unroll
    for (int i = 0; i < 4; ++i) {
      const int rl = srow + i * 8;
      const int gA = sslot ^ (rl & 7);
      const u16* ga = A + (size_t)(m0 + rl) * K + kt + gA * 8;
      u16* la = sA + (wave * 32 + i * 8) * 64;
      __builtin_amdgcn_global_load_lds((const __attribute__((address_space(1))) void*)ga,
                                       (__attribute__((address_space(3))) void*)la, 16, 0, 0);
    }
#pragma unroll
    for (int i = 0; i < 4; ++i) {
      const int rl = srow + i * 8;
      const int gB = sslot ^ (rl & 7);
      const u16* gb = BT + (size_t)(n0 + rl) * K + kt + gB * 8;
      u16* lb = sB + (wave * 32 + i * 8) * 64;
      __builtin_amdgcn_global_load_lds((const __attribute__((address_space(1))) void*)gb,
                                       (__attribute__((address_space(3))) void*)lb, 16, 0, 0);
    }
    __syncthreads();
    const int fr = lane & 15, fq = lane >> 4;
#pragma unroll
    for (int ks = 0; ks < 2; ++ks) {
      short8 af[4], bfr[4];
#pragma unroll
      for (int i = 0; i < 4; ++i) {
        const int rl = wm + i * 16 + fr;
        const int g = ks * 4 + fq;
        af[i] = *(const short8*)(sA + rl * 64 + (g ^ (rl & 7)) * 8);
      }
#pragma unroll
      for (int j = 0; j < 4; ++j) {
        const int rl = wn + j * 16 + fr;
        const int g = ks * 4 + fq;
        bfr[j] = *(const short8*)(sB + rl * 64 + (g ^ (rl & 7)) * 8);
      }
#pragma unroll
      for (int i = 0; i < 4; ++i)
#pragma unroll
        for (int j = 0; j < 4; ++j)
          acc[i][j] = __builtin_amdgcn_mfma_f32_16x16x32_bf16(af[i], bfr[j], acc[i][j], 0, 0, 0);
    }
    __syncthreads();
  }

  const int fr = lane & 15, fq = lane >> 4;
#pragma unroll
  for (int i = 0; i < 4; ++i)
#pragma unroll
    for (int j = 0; j < 4; ++j)
#pragma unroll
      for (int r = 0; r < 4; ++r) {
        const int m = m0 + wm + i * 16 + fq * 4 + r;
        const int n = n0 + wn + j * 16 + fr;
        const float v = acc[i][j][r] + bias[n];
        if (EPI == 0)
          outB[(size_t)m * N + n] = f2bf(v);
        else
          outF[(size_t)m * N + n] = v + extra[(size_t)m * N + n];
      }
}

// ---------------- attn1 stage A: scores S[bh][a][n] ----------------
__global__ __launch_bounds__(256) void attn1_scores(const u16* __restrict__ qkv,
                                                    const float* __restrict__ q_anchor,
                                                    float* __restrict__ S) {
  __shared__ float qa[8][128];
  const int tid = threadIdx.x;
  const int chunk = blockIdx.x & 7, bh = blockIdx.x >> 3;
  const int b = bh >> 3, h = bh & 7;
  for (int i = tid; i < 1024; i += 256) qa[i >> 7][i & 127] = q_anchor[h * 1024 + i];
  __syncthreads();
  const float scale = 0.0883883476483184f;
  const int n = chunk * 256 + tid;
  const u16* kp = qkv + (size_t)(b * 2048 + n) * 3072 + 1024 + h * 128;
  float dots[8] = {0, 0, 0, 0, 0, 0, 0, 0};
#pragma unroll 8
  for (int dd = 0; dd < 128; dd += 4) {
    const ushort4 k4 = *(const ushort4*)(kp + dd);
    const float k0 = bf2f(k4.x), k1 = bf2f(k4.y), k2 = bf2f(k4.z), k3 = bf2f(k4.w);
#pragma unroll
    for (int a = 0; a < 8; ++a) {
      const float4 q4 = *(const float4*)&qa[a][dd];
      dots[a] += q4.x * k0 + q4.y * k1 + q4.z * k2 + q4.w * k3;
    }
  }
#pragma unroll
  for (int a = 0; a < 8; ++a) S[((size_t)(bh * 8 + a)) * 2048 + n] = dots[a] * scale;
}

// ---------------- attn1 stage B: row softmax over 2048, in place ----------------
__global__ __launch_bounds__(256) void attn1_softmax(float* __restrict__ S) {
  const int row = blockIdx.x;
  const int tid = threadIdx.x;
  float* Sp = S + (size_t)row * 2048;
  float4 v0 = ((const float4*)Sp)[tid * 2];
  float4 v1 = ((const float4*)Sp)[tid * 2 + 1];
  float mx = fmaxf(fmaxf(fmaxf(v0.x, v0.y), fmaxf(v0.z, v0.w)),
                   fmaxf(fmaxf(v1.x, v1.y), fmaxf(v1.z, v1.w)));
#pragma unroll
  for (int o = 32; o > 0; o >>= 1) mx = fmaxf(mx, __shfl_xor(mx, o));
  __shared__ float red[4];
  const int wv = tid >> 6, ln = tid & 63;
  if (ln == 0) red[wv] = mx;
  __syncthreads();
  mx = fmaxf(fmaxf(red[0], red[1]), fmaxf(red[2], red[3]));
  v0.x = __expf(v0.x - mx); v0.y = __expf(v0.y - mx);
  v0.z = __expf(v0.z - mx); v0.w = __expf(v0.w - mx);
  v1.x = __expf(v1.x - mx); v1.y = __expf(v1.y - mx);
  v1.z = __expf(v1.z - mx); v1.w = __expf(v1.w - mx);
  float sum = v0.x + v0.y + v0.z + v0.w + v1.x + v1.y + v1.z + v1.w;
#pragma unroll
  for (int o = 32; o > 0; o >>= 1) sum += __shfl_xor(sum, o);
  __shared__ float red2[4];
  if (ln == 0) red2[wv] = sum;
  __syncthreads();
  const float inv = 1.f / (red2[0] + red2[1] + red2[2] + red2[3]);
  v0.x *= inv; v0.y *= inv; v0.z *= inv; v0.w *= inv;
  v1.x *= inv; v1.y *= inv; v1.z *= inv; v1.w *= inv;
  ((float4*)Sp)[tid * 2] = v0;
  ((float4*)Sp)[tid * 2 + 1] = v1;
}

// ---------------- attn1 stage C: partial PV -> pvpart[16 splits][64][1024] ----------------
__global__ __launch_bounds__(256) void attn1_pv(const u16* __restrict__ qkv,
                                                const float* __restrict__ S,
                                                float* __restrict__ pvpart) {
  __shared__ float P[8][256];
  const int tid = threadIdx.x;
  const int chunk = blockIdx.x & 7, bh = blockIdx.x >> 3;
  const int b = bh >> 3, h = bh & 7;
  for (int i = tid; i < 2048; i += 256) {
    const int a = i >> 8, n = i & 255;
    P[a][n] = S[((size_t)(bh * 8 + a)) * 2048 + chunk * 256 + n];
  }
  __syncthreads();
  const int d = tid & 127, half = tid >> 7;
  const int nbase = chunk * 256 + half * 128;
  const u16* vp = qkv + (size_t)(b * 2048 + nbase) * 3072 + 2048 + h * 128 + d;
  float acc[8] = {0.f};
  for (int n = 0; n < 128; n += 4) {
    const float v0 = bf2f(vp[(size_t)n * 3072]);
    const float v1 = bf2f(vp[(size_t)(n + 1) * 3072]);
    const float v2 = bf2f(vp[(size_t)(n + 2) * 3072]);
    const float v3 = bf2f(vp[(size_t)(n + 3) * 3072]);
#pragma unroll
    for (int a = 0; a < 8; ++a) {
      const float4 s4 = *(const float4*)&P[a][half * 128 + n];
      acc[a] += s4.x * v0 + s4.y * v1 + s4.z * v2 + s4.w * v3;
    }
  }
  const int split = chunk * 2 + half;
#pragma unroll
  for (int a = 0; a < 8; ++a)
    pvpart[((size_t)split * 64 + bh) * 1024 + a * 128 + d] = acc[a];
}

// ---------------- MLP MFMA GEMM: part[split][64][N] = A[64][Kc] @ W[Kc][N] ----------------
// A f32 row-major (L2-hot, frag loads direct from global); W f32 row-major, staged to
// LDS [n][33] (stride-33 conflict-free), converted bf16 in the fragment load.
__global__ __launch_bounds__(256) void mlp_mfma(const float* __restrict__ A,
                                                const float* __restrict__ W,
                                                float* __restrict__ part,
                                                int K, int N, int KC) {
  __shared__ float sW[64][33];
  const int tid = threadIdx.x;
  const int lane = tid & 63, wave = tid >> 6;
  const int wm = wave * 16;
  const int n0 = blockIdx.x * 64;
  const int kbeg = blockIdx.y * KC;
  const int l15 = lane & 15, kq8 = (lane >> 4) * 8;
  const int arow = wm + l15;

  floatx4 acc[4];
  const floatx4 zero = {0.f, 0.f, 0.f, 0.f};
#pragma unroll
  for (int j = 0; j < 4; ++j) acc[j] = zero;

  for (int kc = 0; kc < KC; kc += 32) {
    const int kbase = kbeg + kc;
    __syncthreads();
    // stage W[kbase..+32)[n0..+64): 8 coalesced rows per wave-slot
#pragma unroll
    for (int p = 0; p < 8; ++p) {
      const int k = p * 4 + wave;
      sW[lane][k] = W[(size_t)(kbase + k) * N + n0 + lane];
    }
    // a-frag direct from global (A is small -> L2)
    const float* ap = A + (size_t)arow * K + kbase + kq8;
    const float4 a0 = *(const float4*)ap;
    const float4 a1 = *(const float4*)(ap + 4);
    short8 af;
    af[0] = (short)f2bf(a0.x); af[1] = (short)f2bf(a0.y);
    af[2] = (short)f2bf(a0.z); af[3] = (short)f2bf(a0.w);
    af[4] = (short)f2bf(a1.x); af[5] = (short)f2bf(a1.y);
    af[6] = (short)f2bf(a1.z); af[7] = (short)f2bf(a1.w);
    __syncthreads();
#pragma unroll
    for (int j = 0; j < 4; ++j) {
      const float* wp = &sW[j * 16 + l15][kq8];
      short8 bf;
      bf[0] = (short)f2bf(wp[0]); bf[1] = (short)f2bf(wp[1]);
      bf[2] = (short)f2bf(wp[2]); bf[3] = (short)f2bf(wp[3]);
      bf[4] = (short)f2bf(wp[4]); bf[5] = (short)f2bf(wp[5]);
      bf[6] = (short)f2bf(wp[6]); bf[7] = (short)f2bf(wp[7]);
      acc[j] = __builtin_amdgcn_mfma_f32_16x16x32_bf16(af, bf, acc[j], 0, 0, 0);
    }
  }
  const int q = lane >> 4;
#pragma unroll
  for (int j = 0; j < 4; ++j)
#pragma unroll
    for (int r = 0; r < 4; ++r) {
      const int m = wm + q * 4 + r;
      const int n = n0 + j * 16 + l15;
      part[((size_t)blockIdx.y * 64 + m) * N + n] = acc[j][r];
    }
}

// ---------------- reduce: out = [relu](sum_s part + bias), optional an-permute ----------------
__global__ __launch_bounds__(256) void mlp_reduce(const float* __restrict__ part,
                                                  const float* __restrict__ bias,
                                                  float* __restrict__ out,
                                                  int N, int nsplit, int relu, int perm) {
  const int idx = blockIdx.x * 256 + threadIdx.x;
  const int e = idx * 4;
  if (e >= 64 * N) return;
  const int row = e / N, col = e - row * N;
  float4 acc;
  if (bias) acc = *(const float4*)&bias[col];
  else { acc.x = 0.f; acc.y = 0.f; acc.z = 0.f; acc.w = 0.f; }
  for (int s = 0; s < nsplit; ++s) {
    const float4 p = *(const float4*)&part[((size_t)s * 64 + row) * N + col];
    acc.x += p.x; acc.y += p.y; acc.z += p.z; acc.w += p.w;
  }
  if (relu) {
    acc.x = fmaxf(acc.x, 0.f); acc.y = fmaxf(acc.y, 0.f);
    acc.z = fmaxf(acc.z, 0.f); acc.w = fmaxf(acc.w, 0.f);
  }
  size_t oidx;
  if (!perm) {
    oidx = (size_t)row * N + col;
  } else {
    const int b = row >> 3, h = row & 7;
    oidx = (size_t)(b * 8 + (col >> 9)) * 4096 + h * 512 + (col & 511);
  }
  *(float4*)&out[oidx] = acc;
}

// ---------------- attention 2: 2048 queries vs 8 anchor keys + PV ----------------
__global__ __launch_bounds__(256) void attn2_kernel(const u16* __restrict__ qkv,
                                                    const float* __restrict__ kk,
                                                    const float* __restrict__ onet,
                                                    u16* __restrict__ y) {
  __shared__ float kkl[8][128];
  __shared__ float ovl[8][128];
  const int tid = threadIdx.x;
  const int chunk = blockIdx.x & 7, bh = blockIdx.x >> 3;
  const int b = bh >> 3, h = bh & 7;
  for (int i = tid; i < 1024; i += 256) {
    const int a = i >> 7, d = i & 127;
    kkl[a][d] = kk[(size_t)(b * 8 + a) * 1024 + h * 128 + d];
    ovl[a][d] = onet[(size_t)(b * 8 + a) * 1024 + h * 128 + d];
  }
  __syncthreads();
  const int n = chunk * 256 + tid;
  const u16* qp = qkv + (size_t)(b * 2048 + n) * 3072 + h * 128;
  float dots[8] = {0, 0, 0, 0, 0, 0, 0, 0};
#pragma unroll 4
  for (int dd = 0; dd < 128; dd += 4) {
    const ushort4 q4 = *(const ushort4*)(qp + dd);
    const float q0 = bf2f(q4.x), q1 = bf2f(q4.y), q2 = bf2f(q4.z), q3 = bf2f(q4.w);
#pragma unroll
    for (int a = 0; a < 8; ++a) {
      const float4 k4 = *(const float4*)&kkl[a][dd];
      dots[a] += k4.x * q0 + k4.y * q1 + k4.z * q2 + k4.w * q3;
    }
  }
  const float scale = 0.0883883476483184f;
  float mx = -1e30f;
#pragma unroll
  for (int a = 0; a < 8; ++a) {
    dots[a] *= scale;
    mx = fmaxf(mx, dots[a]);
  }
  float p[8];
  float sum = 0.f;
#pragma unroll
  for (int a = 0; a < 8; ++a) {
    p[a] = __expf(dots[a] - mx);
    sum += p[a];
  }
  const float inv = 1.f / sum;
#pragma unroll
  for (int a = 0; a < 8; ++a) p[a] *= inv;
  u16* yp = y + (size_t)(b * 2048 + n) * 1024 + h * 128;
#pragma unroll 4
  for (int dd = 0; dd < 128; dd += 4) {
    float a0 = 0, a1 = 0, a2 = 0, a3 = 0;
#pragma unroll
    for (int a = 0; a < 8; ++a) {
      const float4 o4 = *(const float4*)&ovl[a][dd];
      a0 += p[a] * o4.x;
      a1 += p[a] * o4.y;
      a2 += p[a] * o4.z;
      a3 += p[a] * o4.w;
    }
    ushort4 o;
    o.x = f2bf(a0);
    o.y = f2bf(a1);
    o.z = f2bf(a2);
    o.w = f2bf(a3);
    *(ushort4*)(yp + dd) = o;
  }
}

extern "C" void kernel_launch(void* const* d_in, const int* in_sizes, int n_in,
                              void* d_out, int out_size, void* d_ws, size_t ws_size,
                              hipStream_t stream) {
  const float* inputs = (const float*)d_in[0];
  const float* ln_g = (const float*)d_in[1];
  const float* ln_b = (const float*)d_in[2];
  const float* q_anchor = (const float*)d_in[3];
  const float* W_qkv = (const float*)d_in[4];
  const float* b_qkv = (const float*)d_in[5];
  const float* W_an = (const float*)d_in[6];
  const float* b_an = (const float*)d_in[7];
  const float* W_n1 = (const float*)d_in[8];
  const float* b_n1 = (const float*)d_in[9];
  const float* W_n2 = (const float*)d_in[10];
  const float* b_n2 = (const float*)d_in[11];
  const float* W_n3 = (const float*)d_in[12];
  const float* b_n3 = (const float*)d_in[13];
  const float* W_k = (const float*)d_in[14];
  const float* b_k = (const float*)d_in[15];
  const float* W_o = (const float*)d_in[16];
  const float* b_o = (const float*)d_in[17];
  float* out = (float*)d_out;

  char* ws = (char*)d_ws;
  u16* qkv = (u16*)(ws);                                   // 16384*3072 bf16 = 96 MB
  u16* xbf = (u16*)(ws + 100663296);                       // 16384*1024 bf16 (x, later y)
  float* S = (float*)(ws + 100663296);                     // attn1 scores 4 MB (overlays dead x)
  float* part = (float*)(ws + 109051904);                  // pv/mlp partials <=8 MB (dead region)
  u16* WqkvT = (u16*)(ws + 134217728);                     // 3072*1024 bf16
  u16* WoT = (u16*)(ws + 140509184);                       // 1024*1024 bf16
  float* att1 = (float*)(ws + 142606336);                  // 64*1024
  float* anp = (float*)(ws + 142868480);                   // 64*4096
  float* h1 = (float*)(ws + 143917056);                    // 64*1024
  float* h2 = (float*)(ws + 144179200);                    // 64*4096
  float* onet = (float*)(ws + 145227776);                  // 64*1024
  float* kkb = (float*)(ws + 145489920);                   // 64*1024

  // 1) LayerNorm -> x bf16
  ln_kernel<<<16384, 256, 0, stream>>>(inputs, ln_g, ln_b, xbf);
  // 2) weight transpose/convert
  transpose_bf16<<<dim3(32, 96), 256, 0, stream>>>(W_qkv, WqkvT, 1024, 3072);
  transpose_bf16<<<dim3(32, 32), 256, 0, stream>>>(W_o, WoT, 1024, 1024);
  // 3) QKV GEMM -> qkv bf16  (x dead afterwards; S/part overlay it)
  gemm_bf16<0><<<dim3(128, 24), 256, 0, stream>>>(xbf, WqkvT, b_qkv, nullptr, qkv, nullptr,
                                                  16384, 3072, 1024);
  // 4) anchor attention: scores -> softmax -> partial PV -> reduce
  attn1_scores<<<512, 256, 0, stream>>>(qkv, q_anchor, S);
  attn1_softmax<<<512, 256, 0, stream>>>(S);
  attn1_pv<<<512, 256, 0, stream>>>(qkv, S, part);
  mlp_reduce<<<64, 256, 0, stream>>>(part, nullptr, att1, 1024, 16, 0, 0);
  // 5) MLP chain: MFMA split-K GEMMs -> fused reduce(bias/relu/permute)
  mlp_mfma<<<dim3(64, 8), 256, 0, stream>>>(att1, W_an, part, 1024, 4096, 128);
  mlp_reduce<<<256, 256, 0, stream>>>(part, b_an, anp, 4096, 8, 1, 1);
  mlp_mfma<<<dim3(16, 32), 256, 0, stream>>>(anp, W_n1, part, 4096, 1024, 128);
  mlp_reduce<<<64, 256, 0, stream>>>(part, b_n1, h1, 1024, 32, 0, 0);
  mlp_mfma<<<dim3(64, 8), 256, 0, stream>>>(h1, W_n2, part, 1024, 4096, 128);
  mlp_reduce<<<256, 256, 0, stream>>>(part, b_n2, h2, 4096, 8, 1, 0);
  mlp_mfma<<<dim3(16, 32), 256, 0, stream>>>(h2, W_n3, part, 4096, 1024, 128);
  mlp_reduce<<<64, 256, 0, stream>>>(part, b_n3, onet, 1024, 32, 0, 0);
  mlp_mfma<<<dim3(16, 16), 256, 0, stream>>>(onet, W_k, part, 1024, 1024, 64);
  mlp_reduce<<<64, 256, 0, stream>>>(part, b_k, kkb, 1024, 16, 0, 0);
  // 6) query attention over 8 anchors -> y bf16 (reuses xbf buffer; S/part now dead)
  attn2_kernel<<<512, 256, 0, stream>>>(qkv, kkb, onet, xbf);
  // 7) output GEMM + bias + residual -> d_out f32
  gemm_bf16<1><<<dim3(128, 8), 256, 0, stream>>>(xbf, WoT, b_o, inputs, nullptr, out,
                                                 16384, 1024, 1024);
}